// Round 4
// baseline (185.320 us; speedup 1.0000x reference)
//
#include <hip/hip_runtime.h>

// Problem constants (match reference setup_inputs)
#define BB 16
#define SS 2048
#define DD 768
#define D4 (DD / 4)          // 192 float4 per row
#define SPB 16               // output slots per block
#define BLOCKS_PER_ROW (SS / SPB)   // 128

// Native vector type — required by __builtin_nontemporal_store (HIP's
// float4 is a class, not a vector); emits the same global_*_dwordx4.
typedef float vfloat4 __attribute__((ext_vector_type(4)));

// Segment-mean, search-amortized:
//  - 2048 blocks x 256 threads; block = 16 consecutive output slots of one row.
//  - 17 lanes do the 17 lower_bound binary searches IN PARALLEL (the 11-probe
//    dependent-load chain is paid once per block, not once per slot), results
//    in LDS.
//  - Each of the 4 waves then streams 4 slots: count/start come from LDS
//    (no global latency chain in front of the data loads), rows summed with
//    float4 x3 (16 B/lane coalesced), mean stored nontemporally (out is
//    write-once, never read -> don't evict x from L2/L3).
__global__ __launch_bounds__(256) void seg_mean_v3(
    const float* __restrict__ x,
    const int*   __restrict__ seg,
    float*       __restrict__ out) {
    __shared__ int sLb[SPB + 1];

    int b  = blockIdx.x >> 7;                  // / BLOCKS_PER_ROW
    int w0 = (blockIdx.x & (BLOCKS_PER_ROW - 1)) << 4;   // * SPB
    const int* srow = seg + (b << 11);

    if (threadIdx.x <= SPB) {
        // lower_bound(srow, srow+SS, w0 + tid) — 17 parallel searches
        int w  = w0 + threadIdx.x;
        int lo = 0, n = SS;
        while (n > 0) {
            int half = n >> 1;
            int mid  = lo + half;
            if (srow[mid] < w) { lo = mid + 1; n -= half + 1; }
            else               { n = half; }
        }
        sLb[threadIdx.x] = lo;
    }
    __syncthreads();

    int lane = threadIdx.x & 63;
    int wave = threadIdx.x >> 6;
    size_t rowBase = (size_t)(b << 11);

    // each wave handles 4 consecutive slots
    for (int si = (wave << 2); si < (wave << 2) + 4; ++si) {
        int st = sLb[si];
        int c  = sLb[si + 1] - st;
        vfloat4* outp = (vfloat4*)(out + (rowBase + (size_t)(w0 + si)) * DD);

        if (c == 0) {
            vfloat4 z = (vfloat4){0.f, 0.f, 0.f, 0.f};
            __builtin_nontemporal_store(z, &outp[lane]);
            __builtin_nontemporal_store(z, &outp[lane + 64]);
            __builtin_nontemporal_store(z, &outp[lane + 128]);
            continue;
        }

        const vfloat4* xp = (const vfloat4*)(x + (rowBase + (size_t)st) * DD);
        vfloat4 a0 = xp[lane];
        vfloat4 a1 = xp[lane + 64];
        vfloat4 a2 = xp[lane + 128];
        for (int j = 1; j < c; ++j) {
            const vfloat4* xr = xp + (size_t)j * D4;
            a0 += xr[lane];
            a1 += xr[lane + 64];
            a2 += xr[lane + 128];
        }
        float inv = 1.0f / (float)c;
        a0 *= inv;
        a1 *= inv;
        a2 *= inv;
        __builtin_nontemporal_store(a0, &outp[lane]);
        __builtin_nontemporal_store(a1, &outp[lane + 64]);
        __builtin_nontemporal_store(a2, &outp[lane + 128]);
    }
}

extern "C" void kernel_launch(void* const* d_in, const int* in_sizes, int n_in,
                              void* d_out, int out_size, void* d_ws, size_t ws_size,
                              hipStream_t stream) {
    const float* x   = (const float*)d_in[0];   // [B,S,D] fp32
    const int*   seg = (const int*)d_in[1];     // [B,S] int32
    float* out = (float*)d_out;                 // [B,S,D] fp32

    int nBlocks = BB * BLOCKS_PER_ROW;          // 2048
    seg_mean_v3<<<nBlocks, 256, 0, stream>>>(x, seg, out);
}

// Round 5
// 184.793 us; speedup vs baseline: 1.0029x; 1.0029x over previous
//
#include <hip/hip_runtime.h>

// Problem constants
#define BB 16
#define SS 2048
#define DD 768
#define D4 192            // float4 per row
#define P  16             // positions per chunk
#define CPR (SS / P)      // 128 chunks per row
#define PF 8              // load-pipeline depth
#define NT 192            // threads per block (= D4, 3 waves)

typedef float vfloat4 __attribute__((ext_vector_type(4)));

// Streaming segment-mean:
//  - block = (row b, 16-position chunk); thread t owns float4-column t.
//  - seg row (8 KB) preloaded to LDS; all run logic is uniform LDS reads.
//  - ownership: a chunk owns runs STARTING in [p0,p1); the owner of a run
//    also writes the zero rows for empty slots immediately preceding it;
//    the owner of the run containing position SS-1 writes trailing zeros.
//    No inter-block communication needed.
//  - x rows streamed in ascending order through an 8-deep static register
//    pipeline: 8 independent dwordx4 loads always in flight per thread.
//    Refill index clamps to pe-1 (chunk's last needed row) so over-issued
//    refills are L1 hits.
//  - out rows written nontemporally (write-once data; don't evict x).
__global__ __launch_bounds__(NT) void seg_mean_stream(
    const float* __restrict__ x,
    const int*   __restrict__ seg,
    float*       __restrict__ out)
{
    __shared__ __align__(16) int sseg[SS];

    const int b     = blockIdx.x >> 7;          // / CPR
    const int chunk = blockIdx.x & (CPR - 1);
    const int p0 = chunk * P;
    const int p1 = p0 + P;
    const int t  = threadIdx.x;

    // cooperative 8 KB seg-row load (int4, coalesced; L2-hot across blocks)
    {
        const int4* s4 = (const int4*)(seg + (b << 11));
        int4* l4 = (int4*)sseg;
        #pragma unroll
        for (int i = 0; i < 3; ++i) {
            int idx = t + i * NT;
            if (idx < SS / 4) l4[idx] = s4[idx];
        }
    }
    __syncthreads();

    // first owned run start (skip continuation of previous chunk's run)
    const int prev = (p0 == 0) ? -1 : sseg[p0 - 1];
    int p = p0;
    while (p < p1 && sseg[p] == prev) ++p;
    if (p >= p1) return;                        // no owned runs

    // pe = first run-start >= p1 (processing stops exactly there)
    int pe = p1;
    while (pe < SS && sseg[pe] == sseg[pe - 1]) ++pe;

    const vfloat4* xrow = (const vfloat4*)(x + (((size_t)b) << 11) * DD);
    float* outrow = out + (((size_t)b) << 11) * DD;
    const vfloat4 z = (vfloat4){0.f, 0.f, 0.f, 0.f};

    int runid = sseg[p];
    for (int w = prev + 1; w < runid; ++w)      // zeros before first owned run
        __builtin_nontemporal_store(z, (vfloat4*)(outrow + (size_t)w * DD) + t);

    #define LDX(r) (xrow[(size_t)((r) < pe ? (r) : (pe - 1)) * D4 + t])
    vfloat4 v0 = LDX(p + 0), v1 = LDX(p + 1), v2 = LDX(p + 2), v3 = LDX(p + 3);
    vfloat4 v4 = LDX(p + 4), v5 = LDX(p + 5), v6 = LDX(p + 6), v7 = LDX(p + 7);

    vfloat4 sum = z;
    int cnt = 0;
    bool done = false;

    #define STEP(BUF) {                                                       \
        vfloat4 cur = BUF;                                                    \
        BUF = LDX(p + PF);                       /* refill before the wait */ \
        sum += cur; ++cnt;                                                    \
        int pn = p + 1;                                                       \
        int sn = (pn < SS) ? sseg[pn] : -2;                                   \
        if (sn != runid) {                       /* run ends at p */          \
            vfloat4 m = sum * (1.0f / (float)cnt);                            \
            __builtin_nontemporal_store(m,                                    \
                (vfloat4*)(outrow + (size_t)runid * DD) + t);                 \
            if (pn >= SS) {                      /* row end: trailing zeros */\
                for (int w = runid + 1; w < SS; ++w)                          \
                    __builtin_nontemporal_store(z,                            \
                        (vfloat4*)(outrow + (size_t)w * DD) + t);             \
                done = true;                                                  \
            } else if (pn >= p1) {               /* next run not ours */      \
                done = true;                                                  \
            } else {                             /* zeros, then next run */   \
                for (int w = runid + 1; w < sn; ++w)                          \
                    __builtin_nontemporal_store(z,                            \
                        (vfloat4*)(outrow + (size_t)w * DD) + t);             \
                runid = sn; sum = z; cnt = 0;                                 \
            }                                                                 \
        }                                                                     \
        p = pn;                                                               \
    }

    while (!done) {
        STEP(v0); if (done) break;
        STEP(v1); if (done) break;
        STEP(v2); if (done) break;
        STEP(v3); if (done) break;
        STEP(v4); if (done) break;
        STEP(v5); if (done) break;
        STEP(v6); if (done) break;
        STEP(v7); if (done) break;
    }
    #undef STEP
    #undef LDX
}

extern "C" void kernel_launch(void* const* d_in, const int* in_sizes, int n_in,
                              void* d_out, int out_size, void* d_ws, size_t ws_size,
                              hipStream_t stream) {
    const float* x   = (const float*)d_in[0];   // [B,S,D] fp32
    const int*   seg = (const int*)d_in[1];     // [B,S] int32
    float* out = (float*)d_out;                 // [B,S,D] fp32

    int nBlocks = BB * CPR;                     // 2048
    seg_mean_stream<<<nBlocks, NT, 0, stream>>>(x, seg, out);
}

// Round 6
// 181.985 us; speedup vs baseline: 1.0183x; 1.0154x over previous
//
#include <hip/hip_runtime.h>

// Problem constants
#define BB 16
#define SS 2048
#define DD 768
#define D4 192            // float4 per row
#define P  16             // positions per block (chunk)
#define CPR (SS / P)      // 128 chunks per row
#define NT 192            // threads per block = D4 (3 waves); thread t = column t
#define SEGW 64           // staged seg-slice width

typedef float vfloat4 __attribute__((ext_vector_type(4)));

// v6: copy-shaped load phase + memory-quiet consume phase.
//  Phase 1 (unconditional, branch-free): 16 back-to-back dwordx4 loads/thread
//    -> register prefix-sum over rows -> LDS. This is the ONLY place x is
//    read (except rare cross-chunk run tails), so the global-load stream is
//    statically 16-deep per thread: maximal memory-level parallelism.
//  Phase 2 (uniform control flow, LDS + stores only): a chunk owns runs
//    STARTING in [p0,p1). sum(rows lo..hi-1) = prefix[hi-1] - prefix[lo-1]
//    (2 LDS reads), mean -> nontemporal store. Owner also writes zero rows
//    for empty slots preceding each owned run; owner of the row-final run
//    writes trailing zeros. Tails extending past p1: rare direct global
//    reads (L2/L3-hot — the neighbor block staged them).
__global__ __launch_bounds__(NT) void seg_mean_v6(
    const float* __restrict__ x,
    const int*   __restrict__ seg,
    float*       __restrict__ out)
{
    __shared__ __align__(16) vfloat4 q[P * D4];   // 48 KB: prefix rows
    __shared__ int sseg[SEGW + 1];                // sseg[i] = seg[p0-1+i]

    const int b     = blockIdx.x >> 7;            // / CPR
    const int chunk = blockIdx.x & (CPR - 1);
    const int p0 = chunk << 4;
    const int p1 = p0 + P;
    const int t  = threadIdx.x;
    const int* segrow = seg + (b << 11);

    if (t <= SEGW) {
        int idx = p0 - 1 + t;
        int v;
        if (idx < 0) v = -1;                      // before row: virtual id -1
        else if (idx >= SS) v = -2;               // never consulted
        else v = segrow[idx];
        sseg[t] = v;
    }

    // ---- Phase 1: unconditional 16-deep load burst + prefix + LDS dump ----
    const vfloat4* xrow = (const vfloat4*)(x + ((size_t)(b << 11) + p0) * DD);
    vfloat4 v[P];
    #pragma unroll
    for (int r = 0; r < P; ++r) v[r] = xrow[(size_t)r * D4 + t];
    #pragma unroll
    for (int r = 1; r < P; ++r) v[r] += v[r - 1];
    #pragma unroll
    for (int r = 0; r < P; ++r) q[r * D4 + t] = v[r];
    __syncthreads();

    // ---- Phase 2: uniform consume (thread t handles float4-column t) ----
    int prev = sseg[0];                           // id of run containing p0-1
    #define SID(pp) (((pp) - p0 + 1 <= SEGW) ? sseg[(pp) - p0 + 1] : segrow[(pp)])
    int p = p0;
    while (p < p1 && SID(p) == prev) ++p;         // skip continuation run
    if (p >= p1) return;                          // no owned runs (run >= 17)

    float* outrow = out + (size_t)(b << 11) * DD;
    const vfloat4 z = {0.f, 0.f, 0.f, 0.f};
    int w = prev + 1;
    while (p < p1) {                              // p = start of an owned run
        int id = SID(p);
        int e = p + 1;
        while (e < SS && SID(e) == id) ++e;       // run end (may pass p1)

        for (; w < id; ++w)                       // zeros for empty slots
            __builtin_nontemporal_store(z, (vfloat4*)(outrow + (size_t)w * DD) + t);

        int eh = (e < p1 ? e : p1);               // staged part of the run
        vfloat4 s = q[(eh - 1 - p0) * D4 + t];
        if (p > p0) s -= q[(p - 1 - p0) * D4 + t];
        for (int r = p1; r < e; ++r)              // rare cross-chunk tail
            s += ((const vfloat4*)(x + ((size_t)(b << 11) + r) * DD))[t];

        float inv = 1.0f / (float)(e - p);
        __builtin_nontemporal_store(s * inv, (vfloat4*)(outrow + (size_t)id * DD) + t);
        w = id + 1;

        if (e >= SS)                              // row-final run: trailing zeros
            for (; w < SS; ++w)
                __builtin_nontemporal_store(z, (vfloat4*)(outrow + (size_t)w * DD) + t);
        p = e;
    }
    #undef SID
}

extern "C" void kernel_launch(void* const* d_in, const int* in_sizes, int n_in,
                              void* d_out, int out_size, void* d_ws, size_t ws_size,
                              hipStream_t stream) {
    const float* x   = (const float*)d_in[0];   // [B,S,D] fp32
    const int*   seg = (const int*)d_in[1];     // [B,S] int32
    float* out = (float*)d_out;                 // [B,S,D] fp32

    int nBlocks = BB * CPR;                     // 2048
    seg_mean_v6<<<nBlocks, NT, 0, stream>>>(x, seg, out);
}